// Round 1
// baseline (285.431 us; speedup 1.0000x reference)
//
#include <hip/hip_runtime.h>
#include <cstdint>
#include <cstddef>

typedef unsigned short u16;
typedef __attribute__((ext_vector_type(8))) short short8;
typedef __attribute__((ext_vector_type(4))) float v4f;

static constexpr size_t NN = (size_t)2048 * 2048;
#define N2 2048

typedef __attribute__((address_space(1))) const unsigned int guint;
typedef __attribute__((address_space(3))) unsigned int luint;

__device__ __forceinline__ float b2f_bits(uint32_t hi) { union { uint32_t u; float f; } v; v.u = hi; return v.f; }
__device__ __forceinline__ float b2f(u16 x) { return b2f_bits((uint32_t)x << 16); }
__device__ __forceinline__ u16 f2b(float f) {
  union { float f; uint32_t u; } v; v.f = f;
  uint32_t r = v.u + 0x7fffu + ((v.u >> 16) & 1u);
  return (u16)(r >> 16);
}
__device__ __forceinline__ uint2 pack4(const float* f) {
  uint2 u;
  u.x = (uint32_t)f2b(f[0]) | ((uint32_t)f2b(f[1]) << 16);
  u.y = (uint32_t)f2b(f[2]) | ((uint32_t)f2b(f[3]) << 16);
  return u;
}
__device__ __forceinline__ void unp8(uint4 u, float* f) {
  f[0] = b2f_bits(u.x << 16); f[1] = b2f_bits(u.x & 0xffff0000u);
  f[2] = b2f_bits(u.y << 16); f[3] = b2f_bits(u.y & 0xffff0000u);
  f[4] = b2f_bits(u.z << 16); f[5] = b2f_bits(u.z & 0xffff0000u);
  f[6] = b2f_bits(u.w << 16); f[7] = b2f_bits(u.w & 0xffff0000u);
}

// ---------------------------------------------------------------------------
// K0: one pass over fp32 A[5][N][N]: softmax-weighted sums -> abf (bf16,
// row-major), bbt = b^T, a1t = a1^T (bf16 via LDS-tiled transpose), and
// NEW: a1r = a1 row-major (needed by dcol's diag2/colsum streaming pass).
// Blocks with by<8 additionally compute Xwt[k][n] = bf16((X @ W)[n][k]).
// ---------------------------------------------------------------------------
__global__ __launch_bounds__(256, 6) void conv_kernel(
    const float* __restrict__ A, const float* __restrict__ w1,
    const float* __restrict__ w2, const float* __restrict__ w3,
    const float* __restrict__ X, const float* __restrict__ W,
    u16* __restrict__ abf, u16* __restrict__ bbt, u16* __restrict__ a1t,
    u16* __restrict__ a1r, u16* __restrict__ Xwt)
{
  __shared__ float lb[32][33];
  __shared__ float la[32][33];
  const int t = threadIdx.x;
  const int i0 = blockIdx.y * 32, j0 = blockIdx.x * 32;

  float s1[2][5], s2[2][5], s3[2][5];
  {
    const float* wsrc[3] = { w1, w2, w3 };
    float (*sdst[3])[5] = { s1, s2, s3 };
    for (int q = 0; q < 3; ++q)
      for (int c = 0; c < 2; ++c) {
        float v[5], m = -1e30f, sum = 0.f;
        for (int e = 0; e < 5; ++e) { v[e] = wsrc[q][c * 5 + e]; m = fmaxf(m, v[e]); }
        for (int e = 0; e < 5; ++e) { v[e] = expf(v[e] - m); sum += v[e]; }
        for (int e = 0; e < 5; ++e) sdst[q][c][e] = v[e] / sum;
      }
  }

  const int row = t >> 3;         // 0..31
  const int c4 = (t & 7) * 4;     // col base within tile
  float cst[2][4];                // a1 stash

  {
    float fa[5][4];
    for (int e = 0; e < 5; ++e) {
      float4 v = *(const float4*)(A + (size_t)e * NN + (size_t)(i0 + row) * N2 + (j0 + c4));
      fa[e][0] = v.x; fa[e][1] = v.y; fa[e][2] = v.z; fa[e][3] = v.w;
    }
    for (int c = 0; c < 2; ++c) {
      float av[4] = {0,0,0,0}, bv[4] = {0,0,0,0}, cv[4] = {0,0,0,0};
      for (int e = 0; e < 5; ++e)
        #pragma unroll
        for (int u = 0; u < 4; ++u) {
          av[u] += s1[c][e] * fa[e][u];
          bv[u] += s2[c][e] * fa[e][u];
          cv[u] += s3[c][e] * fa[e][u];
        }
      *(uint2*)(abf + (size_t)c * NN + (size_t)(i0 + row) * N2 + (j0 + c4)) = pack4(av);
      *(uint2*)(a1r + (size_t)c * NN + (size_t)(i0 + row) * N2 + (j0 + c4)) = pack4(cv);
      float* ldst = (c == 0) ? &lb[row][c4] : &la[row][c4];
      #pragma unroll
      for (int u = 0; u < 4; ++u) ldst[u] = bv[u];
      #pragma unroll
      for (int u = 0; u < 4; ++u) cst[c][u] = cv[u];
    }
  }
  __syncthreads();
  {
    float t0[4], t1[4];
    #pragma unroll
    for (int u = 0; u < 4; ++u) { t0[u] = lb[c4 + u][row]; t1[u] = la[c4 + u][row]; }
    *(uint2*)(bbt + 0 * NN + (size_t)(j0 + row) * N2 + (i0 + c4)) = pack4(t0);
    *(uint2*)(bbt + 1 * NN + (size_t)(j0 + row) * N2 + (i0 + c4)) = pack4(t1);
  }
  __syncthreads();
  #pragma unroll
  for (int u = 0; u < 4; ++u) { lb[row][c4 + u] = cst[0][u]; la[row][c4 + u] = cst[1][u]; }
  __syncthreads();
  {
    float t0[4], t1[4];
    #pragma unroll
    for (int u = 0; u < 4; ++u) { t0[u] = lb[c4 + u][row]; t1[u] = la[c4 + u][row]; }
    *(uint2*)(a1t + 0 * NN + (size_t)(j0 + row) * N2 + (i0 + c4)) = pack4(t0);
    *(uint2*)(a1t + 1 * NN + (size_t)(j0 + row) * N2 + (i0 + c4)) = pack4(t1);
  }
  // Folded Xw^T compute: 512 blocks x 4 rows = 2048 rows.
  if (blockIdx.y < 8) {
    const int n = (int)(blockIdx.y * 64 + blockIdx.x) * 4 + (t >> 6);
    const int k = t & 63;
    float acc = 0.f;
    for (int m = 0; m < 256; ++m)
      acc += X[n * 256 + m] * W[m * 64 + k];
    Xwt[(size_t)k * N2 + n] = f2b(acc);
  }
}

// ---------------------------------------------------------------------------
// bf16 MFMA GEMM (glds staging, 128x64 tile, BK=64, 256 thr). C = A@B with
// A [M][K] bf16 row-major, Bt [N][K] bf16 K-contiguous.
// Emits: column-sum partials csp[c][16][2048] (fp32, pre-rounding) and
// diag[c][2048] (fp32 diagonal). Output (TOUT=true): Cout = bf16 C^T via
// in-LDS transpose.
// ---------------------------------------------------------------------------
template<bool TOUT>
__global__ __launch_bounds__(256, 5) void gemm_kernel(
    const u16* __restrict__ Ain, const u16* __restrict__ Btin,
    u16* __restrict__ Cout, float* __restrict__ csp, float* __restrict__ diag)
{
  const int c = blockIdx.z;
  const u16* Ac = Ain + (size_t)c * NN;
  const u16* Bc = Btin + (size_t)c * NN;
  const int m0 = blockIdx.y * 128, n0 = blockIdx.x * 64;
  const int t = threadIdx.x, w = t >> 6, lane = t & 63;
  const int quad = lane >> 4, r = lane & 15;
  __shared__ u16 SM[128 * 64 + 64 * 64];   // As | Bs (24 KB)
  u16* As = SM;
  u16* Bs = SM + 128 * 64;

  v4f zero4 = { 0.f, 0.f, 0.f, 0.f };
  v4f acc[2][4];
  #pragma unroll
  for (int i = 0; i < 2; ++i)
    #pragma unroll
    for (int j = 0; j < 4; ++j) acc[i][j] = zero4;

  const int srow = lane >> 3;            // row within an 8-row chunk
  const int sgran = (lane & 7) ^ srow;   // swizzled k-granule

  for (int kt = 0; kt < 2048; kt += 64) {
    __syncthreads();
    #pragma unroll
    for (int i = 0; i < 4; ++i) {
      const int chunk = i * 4 + w;
      const u16* ga = Ac + (size_t)(m0 + chunk * 8 + srow) * N2 + kt + sgran * 8;
      __builtin_amdgcn_global_load_lds((guint*)ga, (luint*)(As + chunk * 512), 16, 0, 0);
    }
    #pragma unroll
    for (int i = 0; i < 2; ++i) {
      const int chunk = i * 4 + w;
      const u16* gb = Bc + (size_t)(n0 + chunk * 8 + srow) * N2 + kt + sgran * 8;
      __builtin_amdgcn_global_load_lds((guint*)gb, (luint*)(Bs + chunk * 512), 16, 0, 0);
    }
    __syncthreads();
    #pragma unroll
    for (int ks = 0; ks < 2; ++ks) {
      const int sl = ((ks * 4 + quad) ^ (r & 7)) * 8;
      short8 af[2], bf[4];
      #pragma unroll
      for (int i = 0; i < 2; ++i)
        af[i] = *(const short8*)(As + (w * 32 + i * 16 + r) * 64 + sl);
      #pragma unroll
      for (int j = 0; j < 4; ++j)
        bf[j] = *(const short8*)(Bs + (j * 16 + r) * 64 + sl);
      #pragma unroll
      for (int i = 0; i < 2; ++i)
        #pragma unroll
        for (int j = 0; j < 4; ++j)
          acc[i][j] = __builtin_amdgcn_mfma_f32_16x16x32_bf16(af[i], bf[j], acc[i][j], 0, 0, 0);
    }
  }
  // C/D layout: col=lane&15, row=quad*4+reg (m89-verified).
  // Diagonal (fp32, pre-rounding).
  if ((int)(blockIdx.x >> 1) == (int)blockIdx.y) {
    #pragma unroll
    for (int i = 0; i < 2; ++i) {
      const int rowg = m0 + w * 32 + i * 16 + quad * 4;
      #pragma unroll
      for (int j = 0; j < 4; ++j) {
        const int colg = n0 + j * 16 + r;
        #pragma unroll
        for (int g = 0; g < 4; ++g)
          if (rowg + g == colg) diag[c * N2 + colg] = acc[i][j][g];
      }
    }
  }
  if constexpr (!TOUT) {
    u16* Cc = Cout + (size_t)c * NN;
    #pragma unroll
    for (int i = 0; i < 2; ++i) {
      const int rowg = m0 + w * 32 + i * 16 + quad * 4;
      #pragma unroll
      for (int j = 0; j < 4; ++j) {
        const int colg = n0 + j * 16 + r;
        #pragma unroll
        for (int g = 0; g < 4; ++g)
          Cc[(size_t)(rowg + g) * N2 + colg] = f2b(acc[i][j][g]);
      }
    }
  }
  // Column-sum partials over this block's 128 rows for its 64 cols.
  float s[4];
  #pragma unroll
  for (int j = 0; j < 4; ++j) {
    s[j] = 0.f;
    #pragma unroll
    for (int i = 0; i < 2; ++i)
      #pragma unroll
      for (int g = 0; g < 4; ++g) s[j] += acc[i][j][g];
    s[j] += __shfl_xor(s[j], 16);
    s[j] += __shfl_xor(s[j], 32);
  }
  __syncthreads();                 // MFMA-loop LDS reads done
  float* csl = (float*)SM;         // [4][64]
  if (quad == 0) {
    #pragma unroll
    for (int j = 0; j < 4; ++j) csl[w * 64 + j * 16 + r] = s[j];
  }
  __syncthreads();
  if (t < 64) {
    const float v = csl[t] + csl[64 + t] + csl[128 + t] + csl[192 + t];
    csp[((size_t)(c * 16) + blockIdx.y) * N2 + n0 + t] = v;
  }
  if constexpr (TOUT) {
    // Transpose tile via LDS (row stride 136 u16 = 272 B, 16-B aligned rows).
    __syncthreads();
    u16* tb = SM;                  // [64][136] u16 = 17.4 KB
    #pragma unroll
    for (int i = 0; i < 2; ++i) {
      #pragma unroll
      for (int j = 0; j < 4; ++j) {
        #pragma unroll
        for (int g = 0; g < 4; ++g)
          tb[(j * 16 + r) * 136 + (w * 32 + i * 16 + quad * 4 + g)] = f2b(acc[i][j][g]);
      }
    }
    __syncthreads();
    u16* Cc = Cout + (size_t)c * NN;
    const int rown = t >> 2, seg = t & 3;
    const u16* ps = tb + rown * 136 + seg * 32;
    uint4* pd = (uint4*)(Cc + (size_t)(n0 + rown) * N2 + m0 + seg * 32);
    pd[0] = ((const uint4*)ps)[0];
    pd[1] = ((const uint4*)ps)[1];
    pd[2] = ((const uint4*)ps)[2];
    pd[3] = ((const uint4*)ps)[3];
  }
}

// ---------------------------------------------------------------------------
// Z-partials via MFMA: Zp[split][c][k][i] partial of sum_j Ht[i][j]*Xwt[k][j]
// over j in split's 128-range. M=2048(i), N=64(k), K=2048(j), K-split 16.
// Output layout is k-major ([..][k][2048 i], float4 stores) so the yfix
// reduction reads i-contiguous.
// ---------------------------------------------------------------------------
__global__ __launch_bounds__(256) void zgemm_kernel(
    const u16* __restrict__ Ht, const u16* __restrict__ Xwt, float* __restrict__ Zp)
{
  const int c = blockIdx.z, split = blockIdx.y;
  const int m0 = blockIdx.x * 128;
  const u16* Ac = Ht + (size_t)c * NN;
  const int t = threadIdx.x, w = t >> 6, lane = t & 63;
  const int quad = lane >> 4, r = lane & 15;
  __shared__ u16 As[128 * 64];
  __shared__ u16 Bs[64 * 64];

  v4f zero4 = { 0.f, 0.f, 0.f, 0.f };
  v4f acc[2][4];
  #pragma unroll
  for (int i = 0; i < 2; ++i)
    #pragma unroll
    for (int j = 0; j < 4; ++j) acc[i][j] = zero4;

  const int srow = lane >> 3;
  const int sgran = (lane & 7) ^ srow;

  for (int kk = 0; kk < 2; ++kk) {
    const int kt = split * 128 + kk * 64;
    __syncthreads();
    #pragma unroll
    for (int i = 0; i < 4; ++i) {
      const int chunk = i * 4 + w;
      const u16* ga = Ac + (size_t)(m0 + chunk * 8 + srow) * N2 + kt + sgran * 8;
      __builtin_amdgcn_global_load_lds((guint*)ga, (luint*)(As + chunk * 512), 16, 0, 0);
    }
    #pragma unroll
    for (int i = 0; i < 2; ++i) {
      const int chunk = i * 4 + w;
      const u16* gb = Xwt + (size_t)(chunk * 8 + srow) * N2 + kt + sgran * 8;
      __builtin_amdgcn_global_load_lds((guint*)gb, (luint*)(Bs + chunk * 512), 16, 0, 0);
    }
    __syncthreads();
    #pragma unroll
    for (int ks = 0; ks < 2; ++ks) {
      const int sl = ((ks * 4 + quad) ^ (r & 7)) * 8;
      short8 af[2], bf[4];
      #pragma unroll
      for (int i = 0; i < 2; ++i)
        af[i] = *(const short8*)(As + (w * 32 + i * 16 + r) * 64 + sl);
      #pragma unroll
      for (int j = 0; j < 4; ++j)
        bf[j] = *(const short8*)(Bs + (j * 16 + r) * 64 + sl);
      #pragma unroll
      for (int i = 0; i < 2; ++i)
        #pragma unroll
        for (int j = 0; j < 4; ++j)
          acc[i][j] = __builtin_amdgcn_mfma_f32_16x16x32_bf16(af[i], bf[j], acc[i][j], 0, 0, 0);
    }
  }
  const size_t pbase = (size_t)(split * 2 + c) * 64;
  #pragma unroll
  for (int i = 0; i < 2; ++i) {
    const int rowg = m0 + w * 32 + i * 16 + quad * 4;
    #pragma unroll
    for (int j = 0; j < 4; ++j) {
      const int colg = j * 16 + r;
      *(v4f*)(Zp + (pbase + colg) * (size_t)N2 + rowg) = acc[i][j];
    }
  }
}

// colinv: ci[c][q] = (deg==0) ? 0 : 1/(deg+eps), deg = sum_s csp[c][s][q] - diag
// Also w2v[c][q] = ci*deg = colsum of Hn column q (== deg/(deg+eps)).
__global__ void colinv_kernel(const float* __restrict__ csp, const float* __restrict__ diag,
                              float* __restrict__ ci, float* __restrict__ wv)
{
  const int idx = blockIdx.x * 256 + threadIdx.x;  // [0, 4096)
  float cs = 0.f;
  const int c = idx >> 11, q = idx & 2047;
  #pragma unroll
  for (int s = 0; s < 16; ++s) cs += csp[((size_t)(c * 16) + s) * N2 + q];
  const float deg = cs - diag[idx];
  const float v = (deg == 0.f) ? 0.f : 1.f / (deg + 1e-8f);
  ci[idx] = v;
  wv[idx] = v * deg;
}

// ---------------------------------------------------------------------------
// dcol: streaming pass over Ht and a1r rows q. Accumulates per-column partials:
//   dacc[p] += ci[q]*Ht[q][p]*a1[q][p]   (q != p)   -> diag(H2) partials
//   cacc[p] += w2v[q]*a1[q][p]                       -> colsum(H2) partials
// Grid (128 row-groups of 16, 2 channels); partials dp/cp [c][128][2048] fp32.
// ---------------------------------------------------------------------------
__global__ __launch_bounds__(256) void dcol_kernel(
    const u16* __restrict__ Ht, const u16* __restrict__ a1r,
    const float* __restrict__ ci, const float* __restrict__ wv,
    float* __restrict__ dp, float* __restrict__ cp)
{
  const int qg = blockIdx.x, c = blockIdx.y;
  const int p0 = threadIdx.x * 8;
  float dacc[8] = {0,0,0,0,0,0,0,0};
  float cacc[8] = {0,0,0,0,0,0,0,0};
  const u16* hb = Ht  + (size_t)c * NN + (size_t)(qg * 16) * N2 + p0;
  const u16* ab = a1r + (size_t)c * NN + (size_t)(qg * 16) * N2 + p0;
  for (int qq = 0; qq < 16; ++qq) {
    const int q = qg * 16 + qq;
    const float cq = ci[c * N2 + q];
    const float wq = wv[c * N2 + q];
    uint4 hu = *(const uint4*)(hb + (size_t)qq * N2);
    uint4 au = *(const uint4*)(ab + (size_t)qq * N2);
    float h[8], a[8];
    unp8(hu, h); unp8(au, a);
    #pragma unroll
    for (int u = 0; u < 8; ++u) {
      cacc[u] += wq * a[u];
      const float tv = cq * h[u] * a[u];
      dacc[u] += (p0 + u == q) ? 0.f : tv;
    }
  }
  float* dd = dp + (size_t)(c * 128 + qg) * N2 + p0;
  float* cd = cp + (size_t)(c * 128 + qg) * N2 + p0;
  v4f d0 = { dacc[0], dacc[1], dacc[2], dacc[3] };
  v4f d1 = { dacc[4], dacc[5], dacc[6], dacc[7] };
  v4f c0 = { cacc[0], cacc[1], cacc[2], cacc[3] };
  v4f c1 = { cacc[4], cacc[5], cacc[6], cacc[7] };
  *(v4f*)dd = d0; *(v4f*)(dd + 4) = d1;
  *(v4f*)cd = c0; *(v4f*)(cd + 4) = c1;
}

// yfix: Y^T[c][k][i] = bf16( ci[i] * (Z[i][k] - diag1[i]*Xw[i][k]) )
// Z reduced from 16 split partials.
__global__ __launch_bounds__(256) void yfix_kernel(
    const float* __restrict__ Zp, const float* __restrict__ ci,
    const float* __restrict__ diag1, const u16* __restrict__ Xwt,
    u16* __restrict__ Yt)
{
  const int idx = blockIdx.x * 256 + threadIdx.x;  // [0, 262144)
  const int i = idx & 2047, k = (idx >> 11) & 63, c = idx >> 17;
  float z = 0.f;
  #pragma unroll
  for (int s = 0; s < 16; ++s)
    z += Zp[(size_t)((s * 2 + c) * 64 + k) * N2 + i];
  const float xw = b2f(Xwt[(size_t)k * N2 + i]);
  const float y = ci[c * N2 + i] * (z - diag1[c * N2 + i] * xw);
  Yt[(size_t)c * 64 * N2 + (size_t)k * N2 + i] = f2b(y);
}

// fin: reduce dp/cp partials -> diag2[c][i], dinv2[c][i]
__global__ void fin_kernel(const float* __restrict__ dp, const float* __restrict__ cp,
                           float* __restrict__ diag2, float* __restrict__ dinv2)
{
  const int idx = blockIdx.x * 256 + threadIdx.x;  // [0, 4096)
  const int c = idx >> 11, i = idx & 2047;
  float ds = 0.f, cs = 0.f;
  for (int b = 0; b < 128; ++b) {
    ds += dp[(size_t)(c * 128 + b) * N2 + i];
    cs += cp[(size_t)(c * 128 + b) * N2 + i];
  }
  const float deg = cs - ds + 1.0f;   // add=True: diag set to 1 contributes +1
  diag2[idx] = ds;
  dinv2[idx] = (deg == 0.f) ? 0.f : 1.f / (deg + 1e-8f);
}

// ---------------------------------------------------------------------------
// T-partials via MFMA: Tp[split][c][i][k] partial of sum_j a1t[i][j]*Yt[c][k][j]
// over j in split's 128-range. M=2048(i), N=64(k), K=2048(j), K-split 16.
// ---------------------------------------------------------------------------
__global__ __launch_bounds__(256) void tgemm_kernel(
    const u16* __restrict__ a1t, const u16* __restrict__ Yt, float* __restrict__ Tp)
{
  const int c = blockIdx.z, split = blockIdx.y;
  const int m0 = blockIdx.x * 128;
  const u16* Ac = a1t + (size_t)c * NN;
  const u16* Bc = Yt + (size_t)c * (64 * (size_t)N2);
  const int t = threadIdx.x, w = t >> 6, lane = t & 63;
  const int quad = lane >> 4, r = lane & 15;
  __shared__ u16 As[128 * 64];
  __shared__ u16 Bs[64 * 64];

  v4f zero4 = { 0.f, 0.f, 0.f, 0.f };
  v4f acc[2][4];
  #pragma unroll
  for (int i = 0; i < 2; ++i)
    #pragma unroll
    for (int j = 0; j < 4; ++j) acc[i][j] = zero4;

  const int srow = lane >> 3;
  const int sgran = (lane & 7) ^ srow;

  for (int kk = 0; kk < 2; ++kk) {
    const int kt = split * 128 + kk * 64;
    __syncthreads();
    #pragma unroll
    for (int i = 0; i < 4; ++i) {
      const int chunk = i * 4 + w;
      const u16* ga = Ac + (size_t)(m0 + chunk * 8 + srow) * N2 + kt + sgran * 8;
      __builtin_amdgcn_global_load_lds((guint*)ga, (luint*)(As + chunk * 512), 16, 0, 0);
    }
    #pragma unroll
    for (int i = 0; i < 2; ++i) {
      const int chunk = i * 4 + w;
      const u16* gb = Bc + (size_t)(chunk * 8 + srow) * N2 + kt + sgran * 8;
      __builtin_amdgcn_global_load_lds((guint*)gb, (luint*)(Bs + chunk * 512), 16, 0, 0);
    }
    __syncthreads();
    #pragma unroll
    for (int ks = 0; ks < 2; ++ks) {
      const int sl = ((ks * 4 + quad) ^ (r & 7)) * 8;
      short8 af[2], bf[4];
      #pragma unroll
      for (int i = 0; i < 2; ++i)
        af[i] = *(const short8*)(As + (w * 32 + i * 16 + r) * 64 + sl);
      #pragma unroll
      for (int j = 0; j < 4; ++j)
        bf[j] = *(const short8*)(Bs + (j * 16 + r) * 64 + sl);
      #pragma unroll
      for (int i = 0; i < 2; ++i)
        #pragma unroll
        for (int j = 0; j < 4; ++j)
          acc[i][j] = __builtin_amdgcn_mfma_f32_16x16x32_bf16(af[i], bf[j], acc[i][j], 0, 0, 0);
    }
  }
  const size_t pbase = (size_t)(split * 2 + c) * 2048;
  #pragma unroll
  for (int i = 0; i < 2; ++i) {
    const int rowg = m0 + w * 32 + i * 16 + quad * 4;
    #pragma unroll
    for (int j = 0; j < 4; ++j) {
      const int colg = j * 16 + r;
      #pragma unroll
      for (int g = 0; g < 4; ++g)
        Tp[(pbase + rowg + g) * 64 + colg] = acc[i][j][g];
    }
  }
}

// out[i][c*64+k] = relu( dinv2 * (T - diag2*xw + xw) ), fp32
__global__ void epilogue_kernel(const float* __restrict__ Tp, const float* __restrict__ diag2,
                                const float* __restrict__ dinv2, const u16* __restrict__ Xwt,
                                float* __restrict__ out)
{
  const int idx = blockIdx.x * 256 + threadIdx.x;
  const int k = idx & 63;
  const int c = (idx >> 6) & 1;
  const int i = idx >> 7;
  float T = 0.f;
  #pragma unroll
  for (int s = 0; s < 16; ++s)
    T += Tp[((size_t)(s * 2 + c) * 2048 + i) * 64 + k];
  const float hd = diag2[c * N2 + i];
  const float dv = dinv2[c * N2 + i];
  const float xw = b2f(Xwt[(size_t)k * N2 + i]);
  float v = dv * (T - hd * xw + xw);
  v = v > 0.f ? v : 0.f;
  out[(size_t)i * 128 + c * 64 + k] = v;
}

// ---------------------------------------------------------------------------
// Workspace layout (bytes), end 84.49 MB, all reads preceded by writes:
//   abf   @ 0          (16.78 MB bf16)  -- dead after gemm1
//   bbt   @ 16777216   (16.78 MB bf16)  -- dead after gemm1
//   a1t   @ 33554432   (16.78 MB bf16)  -- dead after tgemm
//   a1r   @ 50331648   (16.78 MB bf16)  -- dead after dcol
//   Ht    @ 67108864   (16.78 MB bf16)  -- dead after dcol
//   Xwt   @ 83886080   (256 KB bf16 [64][2048])
//   cspa  @ 84148224   (256 KB)
//   diag1 @ 84410368   (16 KB)
//   ci1   @ 84426752   (16 KB)
//   w2v   @ 84443136   (16 KB)
//   diag2 @ 84459520   (16 KB)
//   dinv2 @ 84475904   (16 KB)          -- end 84492288
//   Zp    @ 0          (16.78 MB fp32 [16][2][64][2048], over abf)
//   dp    @ 16777216   (2 MB fp32 [2][128][2048], over bbt)
//   cp    @ 18874368   (2 MB fp32, over bbt)
//   Yt    @ 20971520   (512 KB bf16 [2][64][2048], over bbt)
//   Tp    @ 50331648   (16.78 MB fp32 [16][2][2048][64], over a1r)
// ---------------------------------------------------------------------------
extern "C" void kernel_launch(void* const* d_in, const int* in_sizes, int n_in,
                              void* d_out, int out_size, void* d_ws, size_t ws_size,
                              hipStream_t stream) {
  const float* A  = (const float*)d_in[0];
  const float* X  = (const float*)d_in[1];
  const float* w1 = (const float*)d_in[2];
  const float* w2 = (const float*)d_in[3];
  const float* w3 = (const float*)d_in[4];
  const float* W  = (const float*)d_in[5];
  float* out = (float*)d_out;
  char* ws = (char*)d_ws;

  u16*   abf   = (u16*)(ws + 0);
  u16*   bbt   = (u16*)(ws + 16777216);
  u16*   a1t   = (u16*)(ws + 33554432);
  u16*   a1r   = (u16*)(ws + 50331648);
  u16*   Ht    = (u16*)(ws + 67108864);
  u16*   Xwt   = (u16*)(ws + 83886080);
  float* cspa  = (float*)(ws + 84148224);
  float* diag1 = (float*)(ws + 84410368);
  float* ci1   = (float*)(ws + 84426752);
  float* w2v   = (float*)(ws + 84443136);
  float* diag2 = (float*)(ws + 84459520);
  float* dinv2 = (float*)(ws + 84475904);
  float* Zp    = (float*)(ws + 0);
  float* dp    = (float*)(ws + 16777216);
  float* cp    = (float*)(ws + 18874368);
  u16*   Yt    = (u16*)(ws + 20971520);
  float* Tp    = (float*)(ws + 50331648);

  conv_kernel<<<dim3(64, 64), 256, 0, stream>>>(A, w1, w2, w3, X, W, abf, bbt, a1t, a1r, Xwt);
  gemm_kernel<true><<<dim3(32, 16, 2), 256, 0, stream>>>(abf, bbt, Ht, cspa, diag1);
  zgemm_kernel<<<dim3(16, 16, 2), 256, 0, stream>>>(Ht, Xwt, Zp);
  colinv_kernel<<<16, 256, 0, stream>>>(cspa, diag1, ci1, w2v);
  dcol_kernel<<<dim3(128, 2), 256, 0, stream>>>(Ht, a1r, ci1, w2v, dp, cp);
  yfix_kernel<<<1024, 256, 0, stream>>>(Zp, ci1, diag1, Xwt, Yt);
  fin_kernel<<<16, 256, 0, stream>>>(dp, cp, diag2, dinv2);
  tgemm_kernel<<<dim3(16, 16, 2), 256, 0, stream>>>(a1t, Yt, Tp);
  epilogue_kernel<<<1024, 256, 0, stream>>>(Tp, diag2, dinv2, Xwt, out);
}

// Round 2
// 264.875 us; speedup vs baseline: 1.0776x; 1.0776x over previous
//
#include <hip/hip_runtime.h>
#include <cstdint>
#include <cstddef>

typedef unsigned short u16;
typedef __attribute__((ext_vector_type(8))) short short8;
typedef __attribute__((ext_vector_type(4))) float v4f;

static constexpr size_t NN = (size_t)2048 * 2048;
#define N2 2048

typedef __attribute__((address_space(1))) const unsigned int guint;
typedef __attribute__((address_space(3))) unsigned int luint;

__device__ __forceinline__ float b2f_bits(uint32_t hi) { union { uint32_t u; float f; } v; v.u = hi; return v.f; }
__device__ __forceinline__ float b2f(u16 x) { return b2f_bits((uint32_t)x << 16); }
__device__ __forceinline__ u16 f2b(float f) {
  union { float f; uint32_t u; } v; v.f = f;
  uint32_t r = v.u + 0x7fffu + ((v.u >> 16) & 1u);
  return (u16)(r >> 16);
}
__device__ __forceinline__ uint4 pack8(const float* f) {
  uint4 u;
  u.x = (uint32_t)f2b(f[0]) | ((uint32_t)f2b(f[1]) << 16);
  u.y = (uint32_t)f2b(f[2]) | ((uint32_t)f2b(f[3]) << 16);
  u.z = (uint32_t)f2b(f[4]) | ((uint32_t)f2b(f[5]) << 16);
  u.w = (uint32_t)f2b(f[6]) | ((uint32_t)f2b(f[7]) << 16);
  return u;
}
__device__ __forceinline__ void unp8(uint4 u, float* f) {
  f[0] = b2f_bits(u.x << 16); f[1] = b2f_bits(u.x & 0xffff0000u);
  f[2] = b2f_bits(u.y << 16); f[3] = b2f_bits(u.y & 0xffff0000u);
  f[4] = b2f_bits(u.z << 16); f[5] = b2f_bits(u.z & 0xffff0000u);
  f[6] = b2f_bits(u.w << 16); f[7] = b2f_bits(u.w & 0xffff0000u);
}

// ---------------------------------------------------------------------------
// K0: one pass over fp32 A[5][N][N], 64x64 tiles (grid 32x32, 256 thr,
// thread = 1 row x 16 cols). Outputs abf, a1r row-major and bbt, a1t
// transposed -- ALL stores are 32B/lane with 4 lanes covering a full 128B
// line (fixes the 2.3x HBM write amplification of the 32x32 version).
// Transposes: 4 LDS tiles u16[64][72], written pre-transposed (scalar u16
// writes), read back as aligned uint4 (conflict-free), single sync.
// Blocks with by<16 additionally compute Xwt[k][n] = bf16((X @ W)[n][k]).
// ---------------------------------------------------------------------------
__global__ __launch_bounds__(256, 2) void conv_kernel(
    const float* __restrict__ A, const float* __restrict__ w1,
    const float* __restrict__ w2, const float* __restrict__ w3,
    const float* __restrict__ X, const float* __restrict__ W,
    u16* __restrict__ abf, u16* __restrict__ bbt, u16* __restrict__ a1t,
    u16* __restrict__ a1r, u16* __restrict__ Xwt)
{
  __shared__ u16 LT[4][64][72];   // [b0,b1,a1_0,a1_1], stored transposed: [n][m]
  const int t = threadIdx.x;
  const int i0 = blockIdx.y * 64, j0 = blockIdx.x * 64;

  const int row = t >> 2;          // 0..63 (tile row m)
  const int cq = (t & 3) * 16;     // col base (tile col n), 16 cols/thread

  float fa[5][16];
  #pragma unroll
  for (int e = 0; e < 5; ++e) {
    const float* base = A + (size_t)e * NN + (size_t)(i0 + row) * N2 + (j0 + cq);
    #pragma unroll
    for (int m = 0; m < 4; ++m) {
      float4 v = *(const float4*)(base + m * 4);
      fa[e][m * 4 + 0] = v.x; fa[e][m * 4 + 1] = v.y;
      fa[e][m * 4 + 2] = v.z; fa[e][m * 4 + 3] = v.w;
    }
  }

  const float* wsrc[3] = { w1, w2, w3 };
  #pragma unroll
  for (int c = 0; c < 2; ++c) {
    float sc[3][5];
    #pragma unroll
    for (int q = 0; q < 3; ++q) {
      float v[5], mx = -1e30f, sum = 0.f;
      #pragma unroll
      for (int e = 0; e < 5; ++e) { v[e] = wsrc[q][c * 5 + e]; mx = fmaxf(mx, v[e]); }
      #pragma unroll
      for (int e = 0; e < 5; ++e) { v[e] = expf(v[e] - mx); sum += v[e]; }
      #pragma unroll
      for (int e = 0; e < 5; ++e) sc[q][e] = v[e] / sum;
    }
    float av[16], bv[16], cv[16];
    #pragma unroll
    for (int u = 0; u < 16; ++u) { av[u] = 0.f; bv[u] = 0.f; cv[u] = 0.f; }
    #pragma unroll
    for (int e = 0; e < 5; ++e)
      #pragma unroll
      for (int u = 0; u < 16; ++u) {
        av[u] += sc[0][e] * fa[e][u];
        bv[u] += sc[1][e] * fa[e][u];
        cv[u] += sc[2][e] * fa[e][u];
      }
    {
      uint4* pa = (uint4*)(abf + (size_t)c * NN + (size_t)(i0 + row) * N2 + (j0 + cq));
      pa[0] = pack8(av); pa[1] = pack8(av + 8);
      uint4* pr = (uint4*)(a1r + (size_t)c * NN + (size_t)(i0 + row) * N2 + (j0 + cq));
      pr[0] = pack8(cv); pr[1] = pack8(cv + 8);
    }
    #pragma unroll
    for (int u = 0; u < 16; ++u) {
      LT[c][cq + u][row]     = f2b(bv[u]);
      LT[2 + c][cq + u][row] = f2b(cv[u]);
    }
  }
  __syncthreads();
  {
    const int on = t >> 2;          // output row (tile col n)
    const int om = (t & 3) * 16;    // output col base (tile row m)
    #pragma unroll
    for (int c = 0; c < 2; ++c) {
      const uint4* pb = (const uint4*)&LT[c][on][om];
      uint4* pd = (uint4*)(bbt + (size_t)c * NN + (size_t)(j0 + on) * N2 + (i0 + om));
      pd[0] = pb[0]; pd[1] = pb[1];
      const uint4* pc = (const uint4*)&LT[2 + c][on][om];
      uint4* pe = (uint4*)(a1t + (size_t)c * NN + (size_t)(j0 + on) * N2 + (i0 + om));
      pe[0] = pc[0]; pe[1] = pc[1];
    }
  }
  // Folded Xw^T compute: 512 blocks x 4 rows = 2048 rows.
  if (blockIdx.y < 16) {
    const int n = (int)(blockIdx.y * 32 + blockIdx.x) * 4 + (t >> 6);
    const int k = t & 63;
    float acc = 0.f;
    for (int m = 0; m < 256; ++m)
      acc += X[n * 256 + m] * W[m * 64 + k];
    Xwt[(size_t)k * N2 + n] = f2b(acc);
  }
}

// ---------------------------------------------------------------------------
// bf16 MFMA GEMM (glds staging, 128x128 tile, BK=64, 256 thr). C = A@B with
// A [M][K] bf16 row-major, Bt [N][K] bf16 K-contiguous.
// Emits: column-sum partials csp[c][16][2048] (fp32, pre-rounding) and
// diag[c][2048] (fp32 diagonal). Output (TOUT=true): Cout = bf16 C^T via
// two-half in-LDS transpose.
// ---------------------------------------------------------------------------
template<bool TOUT>
__global__ __launch_bounds__(256, 3) void gemm_kernel(
    const u16* __restrict__ Ain, const u16* __restrict__ Btin,
    u16* __restrict__ Cout, float* __restrict__ csp, float* __restrict__ diag)
{
  const int c = blockIdx.z;
  const u16* Ac = Ain + (size_t)c * NN;
  const u16* Bc = Btin + (size_t)c * NN;
  const int m0 = blockIdx.y * 128, n0 = blockIdx.x * 128;
  const int t = threadIdx.x, w = t >> 6, lane = t & 63;
  const int quad = lane >> 4, r = lane & 15;
  __shared__ u16 SM[128 * 64 + 128 * 64];   // As | Bs (32 KB)
  u16* As = SM;
  u16* Bs = SM + 128 * 64;

  v4f zero4 = { 0.f, 0.f, 0.f, 0.f };
  v4f acc[2][8];
  #pragma unroll
  for (int i = 0; i < 2; ++i)
    #pragma unroll
    for (int j = 0; j < 8; ++j) acc[i][j] = zero4;

  const int srow = lane >> 3;            // row within an 8-row chunk
  const int sgran = (lane & 7) ^ srow;   // swizzled k-granule

  for (int kt = 0; kt < 2048; kt += 64) {
    __syncthreads();
    #pragma unroll
    for (int i = 0; i < 4; ++i) {
      const int chunk = i * 4 + w;
      const u16* ga = Ac + (size_t)(m0 + chunk * 8 + srow) * N2 + kt + sgran * 8;
      __builtin_amdgcn_global_load_lds((guint*)ga, (luint*)(As + chunk * 512), 16, 0, 0);
    }
    #pragma unroll
    for (int i = 0; i < 4; ++i) {
      const int chunk = i * 4 + w;
      const u16* gb = Bc + (size_t)(n0 + chunk * 8 + srow) * N2 + kt + sgran * 8;
      __builtin_amdgcn_global_load_lds((guint*)gb, (luint*)(Bs + chunk * 512), 16, 0, 0);
    }
    __syncthreads();
    #pragma unroll
    for (int ks = 0; ks < 2; ++ks) {
      const int sl = ((ks * 4 + quad) ^ (r & 7)) * 8;
      short8 af[2], bf[8];
      #pragma unroll
      for (int i = 0; i < 2; ++i)
        af[i] = *(const short8*)(As + (w * 32 + i * 16 + r) * 64 + sl);
      #pragma unroll
      for (int j = 0; j < 8; ++j)
        bf[j] = *(const short8*)(Bs + (j * 16 + r) * 64 + sl);
      #pragma unroll
      for (int i = 0; i < 2; ++i)
        #pragma unroll
        for (int j = 0; j < 8; ++j)
          acc[i][j] = __builtin_amdgcn_mfma_f32_16x16x32_bf16(af[i], bf[j], acc[i][j], 0, 0, 0);
    }
  }
  // C/D layout: col=lane&15, row=quad*4+reg (m89-verified).
  // Diagonal (fp32, pre-rounding).
  if (blockIdx.x == blockIdx.y) {
    #pragma unroll
    for (int i = 0; i < 2; ++i) {
      const int rowg = m0 + w * 32 + i * 16 + quad * 4;
      #pragma unroll
      for (int j = 0; j < 8; ++j) {
        const int colg = n0 + j * 16 + r;
        #pragma unroll
        for (int g = 0; g < 4; ++g)
          if (rowg + g == colg) diag[c * N2 + colg] = acc[i][j][g];
      }
    }
  }
  if constexpr (!TOUT) {
    u16* Cc = Cout + (size_t)c * NN;
    #pragma unroll
    for (int i = 0; i < 2; ++i) {
      const int rowg = m0 + w * 32 + i * 16 + quad * 4;
      #pragma unroll
      for (int j = 0; j < 8; ++j) {
        const int colg = n0 + j * 16 + r;
        #pragma unroll
        for (int g = 0; g < 4; ++g)
          Cc[(size_t)(rowg + g) * N2 + colg] = f2b(acc[i][j][g]);
      }
    }
  }
  // Column-sum partials over this block's 128 rows for its 128 cols.
  float s[8];
  #pragma unroll
  for (int j = 0; j < 8; ++j) {
    s[j] = 0.f;
    #pragma unroll
    for (int i = 0; i < 2; ++i)
      #pragma unroll
      for (int g = 0; g < 4; ++g) s[j] += acc[i][j][g];
    s[j] += __shfl_xor(s[j], 16);
    s[j] += __shfl_xor(s[j], 32);
  }
  __syncthreads();                 // MFMA-loop LDS reads done
  float* csl = (float*)SM;         // [4][128]
  if (quad == 0) {
    #pragma unroll
    for (int j = 0; j < 8; ++j) csl[w * 128 + j * 16 + r] = s[j];
  }
  __syncthreads();
  if (t < 128) {
    const float v = csl[t] + csl[128 + t] + csl[256 + t] + csl[384 + t];
    csp[((size_t)(c * 16) + blockIdx.y) * N2 + n0 + t] = v;
  }
  if constexpr (TOUT) {
    // Two-half transpose via LDS (row stride 136 u16 = 272 B, 16-B aligned).
    u16* tb = SM;                  // [64][136] u16 = 17.4 KB
    u16* Cc = Cout + (size_t)c * NN;
    #pragma unroll
    for (int h = 0; h < 2; ++h) {
      __syncthreads();
      #pragma unroll
      for (int i = 0; i < 2; ++i) {
        #pragma unroll
        for (int jl = 0; jl < 4; ++jl) {
          const int j = h * 4 + jl;
          #pragma unroll
          for (int g = 0; g < 4; ++g)
            tb[(jl * 16 + r) * 136 + (w * 32 + i * 16 + quad * 4 + g)] = f2b(acc[i][j][g]);
        }
      }
      __syncthreads();
      const int rown = t >> 2, seg = t & 3;
      const u16* ps = tb + rown * 136 + seg * 32;
      uint4* pd = (uint4*)(Cc + (size_t)(n0 + h * 64 + rown) * N2 + m0 + seg * 32);
      pd[0] = ((const uint4*)ps)[0];
      pd[1] = ((const uint4*)ps)[1];
      pd[2] = ((const uint4*)ps)[2];
      pd[3] = ((const uint4*)ps)[3];
    }
  }
}

// ---------------------------------------------------------------------------
// Z-partials via MFMA: Zp[split][c][k][i] partial of sum_j Ht[i][j]*Xwt[k][j]
// over j in split's 128-range. M=2048(i), N=64(k), K=2048(j), K-split 16.
// Blocks (0,0,c) additionally run the colinv epilogue for channel c
// (cspa/diag1 are complete: gemm1 finished before this kernel launches):
//   ci[c][q] = (deg==0)?0:1/(deg+eps); wv[c][q] = ci*deg.
// ---------------------------------------------------------------------------
__global__ __launch_bounds__(256) void zgemm_kernel(
    const u16* __restrict__ Ht, const u16* __restrict__ Xwt, float* __restrict__ Zp,
    const float* __restrict__ csp, const float* __restrict__ diag,
    float* __restrict__ ci, float* __restrict__ wv)
{
  const int c = blockIdx.z, split = blockIdx.y;
  const int m0 = blockIdx.x * 128;
  const u16* Ac = Ht + (size_t)c * NN;
  const int t = threadIdx.x, w = t >> 6, lane = t & 63;
  const int quad = lane >> 4, r = lane & 15;
  __shared__ u16 As[128 * 64];
  __shared__ u16 Bs[64 * 64];

  v4f zero4 = { 0.f, 0.f, 0.f, 0.f };
  v4f acc[2][4];
  #pragma unroll
  for (int i = 0; i < 2; ++i)
    #pragma unroll
    for (int j = 0; j < 4; ++j) acc[i][j] = zero4;

  const int srow = lane >> 3;
  const int sgran = (lane & 7) ^ srow;

  for (int kk = 0; kk < 2; ++kk) {
    const int kt = split * 128 + kk * 64;
    __syncthreads();
    #pragma unroll
    for (int i = 0; i < 4; ++i) {
      const int chunk = i * 4 + w;
      const u16* ga = Ac + (size_t)(m0 + chunk * 8 + srow) * N2 + kt + sgran * 8;
      __builtin_amdgcn_global_load_lds((guint*)ga, (luint*)(As + chunk * 512), 16, 0, 0);
    }
    #pragma unroll
    for (int i = 0; i < 2; ++i) {
      const int chunk = i * 4 + w;
      const u16* gb = Xwt + (size_t)(chunk * 8 + srow) * N2 + kt + sgran * 8;
      __builtin_amdgcn_global_load_lds((guint*)gb, (luint*)(Bs + chunk * 512), 16, 0, 0);
    }
    __syncthreads();
    #pragma unroll
    for (int ks = 0; ks < 2; ++ks) {
      const int sl = ((ks * 4 + quad) ^ (r & 7)) * 8;
      short8 af[2], bf[4];
      #pragma unroll
      for (int i = 0; i < 2; ++i)
        af[i] = *(const short8*)(As + (w * 32 + i * 16 + r) * 64 + sl);
      #pragma unroll
      for (int j = 0; j < 4; ++j)
        bf[j] = *(const short8*)(Bs + (j * 16 + r) * 64 + sl);
      #pragma unroll
      for (int i = 0; i < 2; ++i)
        #pragma unroll
        for (int j = 0; j < 4; ++j)
          acc[i][j] = __builtin_amdgcn_mfma_f32_16x16x32_bf16(af[i], bf[j], acc[i][j], 0, 0, 0);
    }
  }
  const size_t pbase = (size_t)(split * 2 + c) * 64;
  #pragma unroll
  for (int i = 0; i < 2; ++i) {
    const int rowg = m0 + w * 32 + i * 16 + quad * 4;
    #pragma unroll
    for (int j = 0; j < 4; ++j) {
      const int colg = j * 16 + r;
      *(v4f*)(Zp + (pbase + colg) * (size_t)N2 + rowg) = acc[i][j];
    }
  }
  // Fused colinv for channel c (2 blocks do this; saves a launch).
  if (blockIdx.x == 0 && blockIdx.y == 0) {
    for (int q = t; q < 2048; q += 256) {
      float cs = 0.f;
      #pragma unroll
      for (int s = 0; s < 16; ++s) cs += csp[((size_t)(c * 16) + s) * N2 + q];
      const float deg = cs - diag[c * N2 + q];
      const float v = (deg == 0.f) ? 0.f : 1.f / (deg + 1e-8f);
      ci[c * N2 + q] = v;
      wv[c * N2 + q] = v * deg;
    }
  }
}

// ---------------------------------------------------------------------------
// dcol: streaming pass over Ht and a1r rows q. Accumulates per-column partials:
//   dacc[p] += ci[q]*Ht[q][p]*a1[q][p]   (q != p)   -> diag(H2) partials
//   cacc[p] += w2v[q]*a1[q][p]                       -> colsum(H2) partials
// Grid (128 row-groups of 16, 2 channels); partials dp/cp [c][128][2048] fp32.
// ---------------------------------------------------------------------------
__global__ __launch_bounds__(256) void dcol_kernel(
    const u16* __restrict__ Ht, const u16* __restrict__ a1r,
    const float* __restrict__ ci, const float* __restrict__ wv,
    float* __restrict__ dp, float* __restrict__ cp)
{
  const int qg = blockIdx.x, c = blockIdx.y;
  const int p0 = threadIdx.x * 8;
  float dacc[8] = {0,0,0,0,0,0,0,0};
  float cacc[8] = {0,0,0,0,0,0,0,0};
  const u16* hb = Ht  + (size_t)c * NN + (size_t)(qg * 16) * N2 + p0;
  const u16* ab = a1r + (size_t)c * NN + (size_t)(qg * 16) * N2 + p0;
  for (int qq = 0; qq < 16; ++qq) {
    const int q = qg * 16 + qq;
    const float cq = ci[c * N2 + q];
    const float wq = wv[c * N2 + q];
    uint4 hu = *(const uint4*)(hb + (size_t)qq * N2);
    uint4 au = *(const uint4*)(ab + (size_t)qq * N2);
    float h[8], a[8];
    unp8(hu, h); unp8(au, a);
    #pragma unroll
    for (int u = 0; u < 8; ++u) {
      cacc[u] += wq * a[u];
      const float tv = cq * h[u] * a[u];
      dacc[u] += (p0 + u == q) ? 0.f : tv;
    }
  }
  float* dd = dp + (size_t)(c * 128 + qg) * N2 + p0;
  float* cd = cp + (size_t)(c * 128 + qg) * N2 + p0;
  v4f d0 = { dacc[0], dacc[1], dacc[2], dacc[3] };
  v4f d1 = { dacc[4], dacc[5], dacc[6], dacc[7] };
  v4f c0 = { cacc[0], cacc[1], cacc[2], cacc[3] };
  v4f c1 = { cacc[4], cacc[5], cacc[6], cacc[7] };
  *(v4f*)dd = d0; *(v4f*)(dd + 4) = d1;
  *(v4f*)cd = c0; *(v4f*)(cd + 4) = c1;
}

// yfix: Y^T[c][k][i] = bf16( ci[i] * (Z[i][k] - diag1[i]*Xw[i][k]) )
// Z reduced from 16 split partials.
__global__ __launch_bounds__(256) void yfix_kernel(
    const float* __restrict__ Zp, const float* __restrict__ ci,
    const float* __restrict__ diag1, const u16* __restrict__ Xwt,
    u16* __restrict__ Yt)
{
  const int idx = blockIdx.x * 256 + threadIdx.x;  // [0, 262144)
  const int i = idx & 2047, k = (idx >> 11) & 63, c = idx >> 17;
  float z = 0.f;
  #pragma unroll
  for (int s = 0; s < 16; ++s)
    z += Zp[(size_t)((s * 2 + c) * 64 + k) * N2 + i];
  const float xw = b2f(Xwt[(size_t)k * N2 + i]);
  const float y = ci[c * N2 + i] * (z - diag1[c * N2 + i] * xw);
  Yt[(size_t)c * 64 * N2 + (size_t)k * N2 + i] = f2b(y);
}

// fin: reduce dp/cp partials -> diag2[c][i], dinv2[c][i]
__global__ void fin_kernel(const float* __restrict__ dp, const float* __restrict__ cp,
                           float* __restrict__ diag2, float* __restrict__ dinv2)
{
  const int idx = blockIdx.x * 256 + threadIdx.x;  // [0, 4096)
  const int c = idx >> 11, i = idx & 2047;
  float ds = 0.f, cs = 0.f;
  for (int b = 0; b < 128; ++b) {
    ds += dp[(size_t)(c * 128 + b) * N2 + i];
    cs += cp[(size_t)(c * 128 + b) * N2 + i];
  }
  const float deg = cs - ds + 1.0f;   // add=True: diag set to 1 contributes +1
  diag2[idx] = ds;
  dinv2[idx] = (deg == 0.f) ? 0.f : 1.f / (deg + 1e-8f);
}

// ---------------------------------------------------------------------------
// T-partials via MFMA: Tp[split][c][i][k] partial of sum_j a1t[i][j]*Yt[c][k][j]
// over j in split's 128-range. M=2048(i), N=64(k), K=2048(j), K-split 16.
// ---------------------------------------------------------------------------
__global__ __launch_bounds__(256) void tgemm_kernel(
    const u16* __restrict__ a1t, const u16* __restrict__ Yt, float* __restrict__ Tp)
{
  const int c = blockIdx.z, split = blockIdx.y;
  const int m0 = blockIdx.x * 128;
  const u16* Ac = a1t + (size_t)c * NN;
  const u16* Bc = Yt + (size_t)c * (64 * (size_t)N2);
  const int t = threadIdx.x, w = t >> 6, lane = t & 63;
  const int quad = lane >> 4, r = lane & 15;
  __shared__ u16 As[128 * 64];
  __shared__ u16 Bs[64 * 64];

  v4f zero4 = { 0.f, 0.f, 0.f, 0.f };
  v4f acc[2][4];
  #pragma unroll
  for (int i = 0; i < 2; ++i)
    #pragma unroll
    for (int j = 0; j < 4; ++j) acc[i][j] = zero4;

  const int srow = lane >> 3;
  const int sgran = (lane & 7) ^ srow;

  for (int kk = 0; kk < 2; ++kk) {
    const int kt = split * 128 + kk * 64;
    __syncthreads();
    #pragma unroll
    for (int i = 0; i < 4; ++i) {
      const int chunk = i * 4 + w;
      const u16* ga = Ac + (size_t)(m0 + chunk * 8 + srow) * N2 + kt + sgran * 8;
      __builtin_amdgcn_global_load_lds((guint*)ga, (luint*)(As + chunk * 512), 16, 0, 0);
    }
    #pragma unroll
    for (int i = 0; i < 2; ++i) {
      const int chunk = i * 4 + w;
      const u16* gb = Bc + (size_t)(chunk * 8 + srow) * N2 + kt + sgran * 8;
      __builtin_amdgcn_global_load_lds((guint*)gb, (luint*)(Bs + chunk * 512), 16, 0, 0);
    }
    __syncthreads();
    #pragma unroll
    for (int ks = 0; ks < 2; ++ks) {
      const int sl = ((ks * 4 + quad) ^ (r & 7)) * 8;
      short8 af[2], bf[4];
      #pragma unroll
      for (int i = 0; i < 2; ++i)
        af[i] = *(const short8*)(As + (w * 32 + i * 16 + r) * 64 + sl);
      #pragma unroll
      for (int j = 0; j < 4; ++j)
        bf[j] = *(const short8*)(Bs + (j * 16 + r) * 64 + sl);
      #pragma unroll
      for (int i = 0; i < 2; ++i)
        #pragma unroll
        for (int j = 0; j < 4; ++j)
          acc[i][j] = __builtin_amdgcn_mfma_f32_16x16x32_bf16(af[i], bf[j], acc[i][j], 0, 0, 0);
    }
  }
  const size_t pbase = (size_t)(split * 2 + c) * 2048;
  #pragma unroll
  for (int i = 0; i < 2; ++i) {
    const int rowg = m0 + w * 32 + i * 16 + quad * 4;
    #pragma unroll
    for (int j = 0; j < 4; ++j) {
      const int colg = j * 16 + r;
      #pragma unroll
      for (int g = 0; g < 4; ++g)
        Tp[(pbase + rowg + g) * 64 + colg] = acc[i][j][g];
    }
  }
}

// out[i][c*64+k] = relu( dinv2 * (T - diag2*xw + xw) ), fp32
__global__ void epilogue_kernel(const float* __restrict__ Tp, const float* __restrict__ diag2,
                                const float* __restrict__ dinv2, const u16* __restrict__ Xwt,
                                float* __restrict__ out)
{
  const int idx = blockIdx.x * 256 + threadIdx.x;
  const int k = idx & 63;
  const int c = (idx >> 6) & 1;
  const int i = idx >> 7;
  float T = 0.f;
  #pragma unroll
  for (int s = 0; s < 16; ++s)
    T += Tp[((size_t)(s * 2 + c) * 2048 + i) * 64 + k];
  const float hd = diag2[c * N2 + i];
  const float dv = dinv2[c * N2 + i];
  const float xw = b2f(Xwt[(size_t)k * N2 + i]);
  float v = dv * (T - hd * xw + xw);
  v = v > 0.f ? v : 0.f;
  out[(size_t)i * 128 + c * 64 + k] = v;
}

// ---------------------------------------------------------------------------
// Workspace layout (bytes), end 84.49 MB, all reads preceded by writes:
//   abf   @ 0          (16.78 MB bf16)  -- dead after gemm1
//   bbt   @ 16777216   (16.78 MB bf16)  -- dead after gemm1
//   a1t   @ 33554432   (16.78 MB bf16)  -- dead after tgemm
//   a1r   @ 50331648   (16.78 MB bf16)  -- dead after dcol
//   Ht    @ 67108864   (16.78 MB bf16)  -- dead after dcol
//   Xwt   @ 83886080   (256 KB bf16 [64][2048])
//   cspa  @ 84148224   (256 KB)
//   diag1 @ 84410368   (16 KB)
//   ci1   @ 84426752   (16 KB)
//   w2v   @ 84443136   (16 KB)
//   diag2 @ 84459520   (16 KB)
//   dinv2 @ 84475904   (16 KB)          -- end 84492288
//   Zp    @ 0          (16.78 MB fp32 [16][2][64][2048], over abf)
//   dp    @ 16777216   (2 MB fp32 [2][128][2048], over bbt)
//   cp    @ 18874368   (2 MB fp32, over bbt)
//   Yt    @ 20971520   (512 KB bf16 [2][64][2048], over bbt)
//   Tp    @ 50331648   (16.78 MB fp32 [16][2][2048][64], over a1r)
// ---------------------------------------------------------------------------
extern "C" void kernel_launch(void* const* d_in, const int* in_sizes, int n_in,
                              void* d_out, int out_size, void* d_ws, size_t ws_size,
                              hipStream_t stream) {
  const float* A  = (const float*)d_in[0];
  const float* X  = (const float*)d_in[1];
  const float* w1 = (const float*)d_in[2];
  const float* w2 = (const float*)d_in[3];
  const float* w3 = (const float*)d_in[4];
  const float* W  = (const float*)d_in[5];
  float* out = (float*)d_out;
  char* ws = (char*)d_ws;

  u16*   abf   = (u16*)(ws + 0);
  u16*   bbt   = (u16*)(ws + 16777216);
  u16*   a1t   = (u16*)(ws + 33554432);
  u16*   a1r   = (u16*)(ws + 50331648);
  u16*   Ht    = (u16*)(ws + 67108864);
  u16*   Xwt   = (u16*)(ws + 83886080);
  float* cspa  = (float*)(ws + 84148224);
  float* diag1 = (float*)(ws + 84410368);
  float* ci1   = (float*)(ws + 84426752);
  float* w2v   = (float*)(ws + 84443136);
  float* diag2 = (float*)(ws + 84459520);
  float* dinv2 = (float*)(ws + 84475904);
  float* Zp    = (float*)(ws + 0);
  float* dp    = (float*)(ws + 16777216);
  float* cp    = (float*)(ws + 18874368);
  u16*   Yt    = (u16*)(ws + 20971520);
  float* Tp    = (float*)(ws + 50331648);

  conv_kernel<<<dim3(32, 32), 256, 0, stream>>>(A, w1, w2, w3, X, W, abf, bbt, a1t, a1r, Xwt);
  gemm_kernel<true><<<dim3(16, 16, 2), 256, 0, stream>>>(abf, bbt, Ht, cspa, diag1);
  zgemm_kernel<<<dim3(16, 16, 2), 256, 0, stream>>>(Ht, Xwt, Zp, cspa, diag1, ci1, w2v);
  dcol_kernel<<<dim3(128, 2), 256, 0, stream>>>(Ht, a1r, ci1, w2v, dp, cp);
  yfix_kernel<<<1024, 256, 0, stream>>>(Zp, ci1, diag1, Xwt, Yt);
  fin_kernel<<<16, 256, 0, stream>>>(dp, cp, diag2, dinv2);
  tgemm_kernel<<<dim3(16, 16, 2), 256, 0, stream>>>(a1t, Yt, Tp);
  epilogue_kernel<<<1024, 256, 0, stream>>>(Tp, diag2, dinv2, Xwt, out);
}

// Round 3
// 246.434 us; speedup vs baseline: 1.1582x; 1.0748x over previous
//
#include <hip/hip_runtime.h>
#include <cstdint>
#include <cstddef>

typedef unsigned short u16;
typedef __attribute__((ext_vector_type(8))) short short8;
typedef __attribute__((ext_vector_type(4))) float v4f;

static constexpr size_t NN = (size_t)2048 * 2048;
#define N2 2048

typedef __attribute__((address_space(1))) const unsigned int guint;
typedef __attribute__((address_space(3))) unsigned int luint;

__device__ __forceinline__ float b2f_bits(uint32_t hi) { union { uint32_t u; float f; } v; v.u = hi; return v.f; }
__device__ __forceinline__ float b2f(u16 x) { return b2f_bits((uint32_t)x << 16); }
__device__ __forceinline__ u16 f2b(float f) {
  union { float f; uint32_t u; } v; v.f = f;
  uint32_t r = v.u + 0x7fffu + ((v.u >> 16) & 1u);
  return (u16)(r >> 16);
}
__device__ __forceinline__ uint4 pack8(const float* f) {
  uint4 u;
  u.x = (uint32_t)f2b(f[0]) | ((uint32_t)f2b(f[1]) << 16);
  u.y = (uint32_t)f2b(f[2]) | ((uint32_t)f2b(f[3]) << 16);
  u.z = (uint32_t)f2b(f[4]) | ((uint32_t)f2b(f[5]) << 16);
  u.w = (uint32_t)f2b(f[6]) | ((uint32_t)f2b(f[7]) << 16);
  return u;
}
__device__ __forceinline__ void unp8(uint4 u, float* f) {
  f[0] = b2f_bits(u.x << 16); f[1] = b2f_bits(u.x & 0xffff0000u);
  f[2] = b2f_bits(u.y << 16); f[3] = b2f_bits(u.y & 0xffff0000u);
  f[4] = b2f_bits(u.z << 16); f[5] = b2f_bits(u.z & 0xffff0000u);
  f[6] = b2f_bits(u.w << 16); f[7] = b2f_bits(u.w & 0xffff0000u);
}
// wave-uniform value -> SGPR (frees a VGPR, enables v_fma with s-operand)
__device__ __forceinline__ float sgprf(float x) {
  union { float f; int i; } v; v.f = x;
  v.i = __builtin_amdgcn_readfirstlane(v.i);
  return v.f;
}

// ---------------------------------------------------------------------------
// K0: one pass over fp32 A[5][N][N], 64x64 tiles, 512 threads, thread =
// 1 row x 8 cols (48 accumulator floats). Softmax weights are hoisted to
// SGPRs via readfirstlane (wave-uniform). Outputs abf, a1r row-major and
// bbt, a1t transposed via XOR-swizzled LDS tiles (64x64 u16, no padding):
// elem (n,m) at n*64 + ((m>>3 ^ n>>3)&7)*8 + (m&7)  -> 2-way write banks
// (free), aligned uint4 reads, 16B/lane global stores (8 lanes = 128B line).
// Blocks with by<8 additionally compute Xwt[k][n] = bf16((X @ W)[n][k]).
// ---------------------------------------------------------------------------
__global__ __launch_bounds__(512, 2) void conv_kernel(
    const float* __restrict__ A, const float* __restrict__ w1,
    const float* __restrict__ w2, const float* __restrict__ w3,
    const float* __restrict__ X, const float* __restrict__ W,
    u16* __restrict__ abf, u16* __restrict__ bbt, u16* __restrict__ a1t,
    u16* __restrict__ a1r, u16* __restrict__ Xwt)
{
  __shared__ u16 LT[4][64 * 64];   // [b0,b1,a1_0,a1_1], transposed+swizzled
  const int t = threadIdx.x;
  const int i0 = blockIdx.y * 64, j0 = blockIdx.x * 64;
  const int m = t >> 3;            // tile row 0..63
  const int cg = t & 7;            // colgroup 0..7
  const int n0 = cg * 8;           // col base

  // softmax weights -> SGPRs (30 scalars)
  float sc[3][2][5];
  {
    const float* wsrc[3] = { w1, w2, w3 };
    for (int q = 0; q < 3; ++q)
      for (int c = 0; c < 2; ++c) {
        float v[5], mx = -1e30f, sum = 0.f;
        #pragma unroll
        for (int e = 0; e < 5; ++e) { v[e] = wsrc[q][c * 5 + e]; mx = fmaxf(mx, v[e]); }
        #pragma unroll
        for (int e = 0; e < 5; ++e) { v[e] = expf(v[e] - mx); sum += v[e]; }
        #pragma unroll
        for (int e = 0; e < 5; ++e) sc[q][c][e] = sgprf(v[e] / sum);
      }
  }

  float av[2][8], bv[2][8], cv[2][8];
  #pragma unroll
  for (int c = 0; c < 2; ++c)
    #pragma unroll
    for (int u = 0; u < 8; ++u) { av[c][u] = 0.f; bv[c][u] = 0.f; cv[c][u] = 0.f; }

  #pragma unroll
  for (int e = 0; e < 5; ++e) {
    const float* base = A + (size_t)e * NN + (size_t)(i0 + m) * N2 + (j0 + n0);
    float4 x0 = ((const float4*)base)[0];
    float4 x1 = ((const float4*)base)[1];
    float f[8] = { x0.x, x0.y, x0.z, x0.w, x1.x, x1.y, x1.z, x1.w };
    #pragma unroll
    for (int c = 0; c < 2; ++c)
      #pragma unroll
      for (int u = 0; u < 8; ++u) {
        av[c][u] += sc[0][c][e] * f[u];
        bv[c][u] += sc[1][c][e] * f[u];
        cv[c][u] += sc[2][c][e] * f[u];
      }
  }

  // row-major outputs: 16B/lane, 8 lanes cover a 128B line
  #pragma unroll
  for (int c = 0; c < 2; ++c) {
    *(uint4*)(abf + (size_t)c * NN + (size_t)(i0 + m) * N2 + (j0 + n0)) = pack8(av[c]);
    *(uint4*)(a1r + (size_t)c * NN + (size_t)(i0 + m) * N2 + (j0 + n0)) = pack8(cv[c]);
  }
  // transposed stash (swizzled scalar stores, 2-way banks)
  const int swb = ((m >> 3) ^ cg) & 7;     // swizzle block for writes (n>>3 == cg)
  const int mlo = m & 7;
  #pragma unroll
  for (int c = 0; c < 2; ++c)
    #pragma unroll
    for (int u = 0; u < 8; ++u) {
      const int idx = (n0 + u) * 64 + swb * 8 + mlo;
      LT[c][idx]     = f2b(bv[c][u]);
      LT[2 + c][idx] = f2b(cv[c][u]);
    }
  __syncthreads();
  {
    const int on = t >> 3;          // output row (tile col n)
    const int mb = t & 7;           // m-block
    const int src = on * 64 + (((mb ^ (on >> 3)) & 7) * 8);
    #pragma unroll
    for (int c = 0; c < 2; ++c) {
      *(uint4*)(bbt + (size_t)c * NN + (size_t)(j0 + on) * N2 + (i0 + mb * 8)) =
          *(const uint4*)&LT[c][src];
      *(uint4*)(a1t + (size_t)c * NN + (size_t)(j0 + on) * N2 + (i0 + mb * 8)) =
          *(const uint4*)&LT[2 + c][src];
    }
  }
  // Folded Xw^T compute: 256 blocks x 8 rows = 2048 rows.
  if (blockIdx.y < 8) {
    const int n = (int)(blockIdx.y * 32 + blockIdx.x) * 8 + (t >> 6);
    const int k = t & 63;
    float acc = 0.f;
    for (int mm = 0; mm < 256; ++mm)
      acc += X[n * 256 + mm] * W[mm * 64 + k];
    Xwt[(size_t)k * N2 + n] = f2b(acc);
  }
}

// ---------------------------------------------------------------------------
// bf16 MFMA GEMM (glds staging, 128x128 tile, BK=64, 256 thr). C = A@B with
// A [M][K] bf16 row-major, Bt [N][K] bf16 K-contiguous.
// Emits: column-sum partials csp[c][16][2048] (fp32, pre-rounding) and
// diag[c][2048] (fp32 diagonal). Output (TOUT=true): Cout = bf16 C^T via
// two-half in-LDS transpose.
// ---------------------------------------------------------------------------
template<bool TOUT>
__global__ __launch_bounds__(256, 3) void gemm_kernel(
    const u16* __restrict__ Ain, const u16* __restrict__ Btin,
    u16* __restrict__ Cout, float* __restrict__ csp, float* __restrict__ diag)
{
  const int c = blockIdx.z;
  const u16* Ac = Ain + (size_t)c * NN;
  const u16* Bc = Btin + (size_t)c * NN;
  const int m0 = blockIdx.y * 128, n0 = blockIdx.x * 128;
  const int t = threadIdx.x, w = t >> 6, lane = t & 63;
  const int quad = lane >> 4, r = lane & 15;
  __shared__ u16 SM[128 * 64 + 128 * 64];   // As | Bs (32 KB)
  u16* As = SM;
  u16* Bs = SM + 128 * 64;

  v4f zero4 = { 0.f, 0.f, 0.f, 0.f };
  v4f acc[2][8];
  #pragma unroll
  for (int i = 0; i < 2; ++i)
    #pragma unroll
    for (int j = 0; j < 8; ++j) acc[i][j] = zero4;

  const int srow = lane >> 3;            // row within an 8-row chunk
  const int sgran = (lane & 7) ^ srow;   // swizzled k-granule

  for (int kt = 0; kt < 2048; kt += 64) {
    __syncthreads();
    #pragma unroll
    for (int i = 0; i < 4; ++i) {
      const int chunk = i * 4 + w;
      const u16* ga = Ac + (size_t)(m0 + chunk * 8 + srow) * N2 + kt + sgran * 8;
      __builtin_amdgcn_global_load_lds((guint*)ga, (luint*)(As + chunk * 512), 16, 0, 0);
    }
    #pragma unroll
    for (int i = 0; i < 4; ++i) {
      const int chunk = i * 4 + w;
      const u16* gb = Bc + (size_t)(n0 + chunk * 8 + srow) * N2 + kt + sgran * 8;
      __builtin_amdgcn_global_load_lds((guint*)gb, (luint*)(Bs + chunk * 512), 16, 0, 0);
    }
    __syncthreads();
    #pragma unroll
    for (int ks = 0; ks < 2; ++ks) {
      const int sl = ((ks * 4 + quad) ^ (r & 7)) * 8;
      short8 af[2], bf[8];
      #pragma unroll
      for (int i = 0; i < 2; ++i)
        af[i] = *(const short8*)(As + (w * 32 + i * 16 + r) * 64 + sl);
      #pragma unroll
      for (int j = 0; j < 8; ++j)
        bf[j] = *(const short8*)(Bs + (j * 16 + r) * 64 + sl);
      #pragma unroll
      for (int i = 0; i < 2; ++i)
        #pragma unroll
        for (int j = 0; j < 8; ++j)
          acc[i][j] = __builtin_amdgcn_mfma_f32_16x16x32_bf16(af[i], bf[j], acc[i][j], 0, 0, 0);
    }
  }
  // C/D layout: col=lane&15, row=quad*4+reg (m89-verified).
  // Diagonal (fp32, pre-rounding).
  if (blockIdx.x == blockIdx.y) {
    #pragma unroll
    for (int i = 0; i < 2; ++i) {
      const int rowg = m0 + w * 32 + i * 16 + quad * 4;
      #pragma unroll
      for (int j = 0; j < 8; ++j) {
        const int colg = n0 + j * 16 + r;
        #pragma unroll
        for (int g = 0; g < 4; ++g)
          if (rowg + g == colg) diag[c * N2 + colg] = acc[i][j][g];
      }
    }
  }
  if constexpr (!TOUT) {
    u16* Cc = Cout + (size_t)c * NN;
    #pragma unroll
    for (int i = 0; i < 2; ++i) {
      const int rowg = m0 + w * 32 + i * 16 + quad * 4;
      #pragma unroll
      for (int j = 0; j < 8; ++j) {
        const int colg = n0 + j * 16 + r;
        #pragma unroll
        for (int g = 0; g < 4; ++g)
          Cc[(size_t)(rowg + g) * N2 + colg] = f2b(acc[i][j][g]);
      }
    }
  }
  // Column-sum partials over this block's 128 rows for its 128 cols.
  float s[8];
  #pragma unroll
  for (int j = 0; j < 8; ++j) {
    s[j] = 0.f;
    #pragma unroll
    for (int i = 0; i < 2; ++i)
      #pragma unroll
      for (int g = 0; g < 4; ++g) s[j] += acc[i][j][g];
    s[j] += __shfl_xor(s[j], 16);
    s[j] += __shfl_xor(s[j], 32);
  }
  __syncthreads();                 // MFMA-loop LDS reads done
  float* csl = (float*)SM;         // [4][128]
  if (quad == 0) {
    #pragma unroll
    for (int j = 0; j < 8; ++j) csl[w * 128 + j * 16 + r] = s[j];
  }
  __syncthreads();
  if (t < 128) {
    const float v = csl[t] + csl[128 + t] + csl[256 + t] + csl[384 + t];
    csp[((size_t)(c * 16) + blockIdx.y) * N2 + n0 + t] = v;
  }
  if constexpr (TOUT) {
    // Two-half transpose via LDS (row stride 136 u16 = 272 B, 16-B aligned).
    u16* tb = SM;                  // [64][136] u16 = 17.4 KB
    u16* Cc = Cout + (size_t)c * NN;
    #pragma unroll
    for (int h = 0; h < 2; ++h) {
      __syncthreads();
      #pragma unroll
      for (int i = 0; i < 2; ++i) {
        #pragma unroll
        for (int jl = 0; jl < 4; ++jl) {
          const int j = h * 4 + jl;
          #pragma unroll
          for (int g = 0; g < 4; ++g)
            tb[(jl * 16 + r) * 136 + (w * 32 + i * 16 + quad * 4 + g)] = f2b(acc[i][j][g]);
        }
      }
      __syncthreads();
      const int rown = t >> 2, seg = t & 3;
      const u16* ps = tb + rown * 136 + seg * 32;
      uint4* pd = (uint4*)(Cc + (size_t)(n0 + h * 64 + rown) * N2 + m0 + seg * 32);
      pd[0] = ((const uint4*)ps)[0];
      pd[1] = ((const uint4*)ps)[1];
      pd[2] = ((const uint4*)ps)[2];
      pd[3] = ((const uint4*)ps)[3];
    }
  }
}

// ---------------------------------------------------------------------------
// Z-partials via MFMA: Zp[split][c][k][i] partial of sum_j Ht[i][j]*Xwt[k][j]
// over j in split's 256-range. M=2048(i), N=64(k), K=2048(j), K-split 8.
// Blocks (0,0,c) additionally run the colinv epilogue for channel c.
// ---------------------------------------------------------------------------
__global__ __launch_bounds__(256) void zgemm_kernel(
    const u16* __restrict__ Ht, const u16* __restrict__ Xwt, float* __restrict__ Zp,
    const float* __restrict__ csp, const float* __restrict__ diag,
    float* __restrict__ ci, float* __restrict__ wv)
{
  const int c = blockIdx.z, split = blockIdx.y;
  const int m0 = blockIdx.x * 128;
  const u16* Ac = Ht + (size_t)c * NN;
  const int t = threadIdx.x, w = t >> 6, lane = t & 63;
  const int quad = lane >> 4, r = lane & 15;
  __shared__ u16 As[128 * 64];
  __shared__ u16 Bs[64 * 64];

  v4f zero4 = { 0.f, 0.f, 0.f, 0.f };
  v4f acc[2][4];
  #pragma unroll
  for (int i = 0; i < 2; ++i)
    #pragma unroll
    for (int j = 0; j < 4; ++j) acc[i][j] = zero4;

  const int srow = lane >> 3;
  const int sgran = (lane & 7) ^ srow;

  for (int kk = 0; kk < 4; ++kk) {
    const int kt = split * 256 + kk * 64;
    __syncthreads();
    #pragma unroll
    for (int i = 0; i < 4; ++i) {
      const int chunk = i * 4 + w;
      const u16* ga = Ac + (size_t)(m0 + chunk * 8 + srow) * N2 + kt + sgran * 8;
      __builtin_amdgcn_global_load_lds((guint*)ga, (luint*)(As + chunk * 512), 16, 0, 0);
    }
    #pragma unroll
    for (int i = 0; i < 2; ++i) {
      const int chunk = i * 4 + w;
      const u16* gb = Xwt + (size_t)(chunk * 8 + srow) * N2 + kt + sgran * 8;
      __builtin_amdgcn_global_load_lds((guint*)gb, (luint*)(Bs + chunk * 512), 16, 0, 0);
    }
    __syncthreads();
    #pragma unroll
    for (int ks = 0; ks < 2; ++ks) {
      const int sl = ((ks * 4 + quad) ^ (r & 7)) * 8;
      short8 af[2], bf[4];
      #pragma unroll
      for (int i = 0; i < 2; ++i)
        af[i] = *(const short8*)(As + (w * 32 + i * 16 + r) * 64 + sl);
      #pragma unroll
      for (int j = 0; j < 4; ++j)
        bf[j] = *(const short8*)(Bs + (j * 16 + r) * 64 + sl);
      #pragma unroll
      for (int i = 0; i < 2; ++i)
        #pragma unroll
        for (int j = 0; j < 4; ++j)
          acc[i][j] = __builtin_amdgcn_mfma_f32_16x16x32_bf16(af[i], bf[j], acc[i][j], 0, 0, 0);
    }
  }
  const size_t pbase = (size_t)(split * 2 + c) * 64;
  #pragma unroll
  for (int i = 0; i < 2; ++i) {
    const int rowg = m0 + w * 32 + i * 16 + quad * 4;
    #pragma unroll
    for (int j = 0; j < 4; ++j) {
      const int colg = j * 16 + r;
      *(v4f*)(Zp + (pbase + colg) * (size_t)N2 + rowg) = acc[i][j];
    }
  }
  // Fused colinv for channel c (2 blocks do this; saves a launch).
  if (blockIdx.x == 0 && blockIdx.y == 0) {
    for (int q = t; q < 2048; q += 256) {
      float cs = 0.f;
      #pragma unroll
      for (int s = 0; s < 16; ++s) cs += csp[((size_t)(c * 16) + s) * N2 + q];
      const float deg = cs - diag[c * N2 + q];
      const float v = (deg == 0.f) ? 0.f : 1.f / (deg + 1e-8f);
      ci[c * N2 + q] = v;
      wv[c * N2 + q] = v * deg;
    }
  }
}

// ---------------------------------------------------------------------------
// dcol: streaming pass over Ht and a1r rows q. Accumulates per-column partials:
//   dacc[p] += ci[q]*Ht[q][p]*a1[q][p]   (q != p)   -> diag(H2) partials
//   cacc[p] += w2v[q]*a1[q][p]                       -> colsum(H2) partials
// Grid (128 row-groups of 16, 2 channels); partials dp/cp [c][128][2048] fp32.
// ---------------------------------------------------------------------------
__global__ __launch_bounds__(256) void dcol_kernel(
    const u16* __restrict__ Ht, const u16* __restrict__ a1r,
    const float* __restrict__ ci, const float* __restrict__ wv,
    float* __restrict__ dp, float* __restrict__ cp)
{
  const int qg = blockIdx.x, c = blockIdx.y;
  const int p0 = threadIdx.x * 8;
  float dacc[8] = {0,0,0,0,0,0,0,0};
  float cacc[8] = {0,0,0,0,0,0,0,0};
  const u16* hb = Ht  + (size_t)c * NN + (size_t)(qg * 16) * N2 + p0;
  const u16* ab = a1r + (size_t)c * NN + (size_t)(qg * 16) * N2 + p0;
  for (int qq = 0; qq < 16; ++qq) {
    const int q = qg * 16 + qq;
    const float cq = ci[c * N2 + q];
    const float wq = wv[c * N2 + q];
    uint4 hu = *(const uint4*)(hb + (size_t)qq * N2);
    uint4 au = *(const uint4*)(ab + (size_t)qq * N2);
    float h[8], a[8];
    unp8(hu, h); unp8(au, a);
    #pragma unroll
    for (int u = 0; u < 8; ++u) {
      cacc[u] += wq * a[u];
      const float tv = cq * h[u] * a[u];
      dacc[u] += (p0 + u == q) ? 0.f : tv;
    }
  }
  float* dd = dp + (size_t)(c * 128 + qg) * N2 + p0;
  float* cd = cp + (size_t)(c * 128 + qg) * N2 + p0;
  v4f d0 = { dacc[0], dacc[1], dacc[2], dacc[3] };
  v4f d1 = { dacc[4], dacc[5], dacc[6], dacc[7] };
  v4f c0 = { cacc[0], cacc[1], cacc[2], cacc[3] };
  v4f c1 = { cacc[4], cacc[5], cacc[6], cacc[7] };
  *(v4f*)dd = d0; *(v4f*)(dd + 4) = d1;
  *(v4f*)cd = c0; *(v4f*)(cd + 4) = c1;
}

// yfix: Y^T[c][k][i] = bf16( ci[i] * (Z[i][k] - diag1[i]*Xw[i][k]) )
// Z reduced from 8 split partials.
__global__ __launch_bounds__(256) void yfix_kernel(
    const float* __restrict__ Zp, const float* __restrict__ ci,
    const float* __restrict__ diag1, const u16* __restrict__ Xwt,
    u16* __restrict__ Yt)
{
  const int idx = blockIdx.x * 256 + threadIdx.x;  // [0, 262144)
  const int i = idx & 2047, k = (idx >> 11) & 63, c = idx >> 17;
  float z = 0.f;
  #pragma unroll
  for (int s = 0; s < 8; ++s)
    z += Zp[(size_t)((s * 2 + c) * 64 + k) * N2 + i];
  const float xw = b2f(Xwt[(size_t)k * N2 + i]);
  const float y = ci[c * N2 + i] * (z - diag1[c * N2 + i] * xw);
  Yt[(size_t)c * 64 * N2 + (size_t)k * N2 + i] = f2b(y);
}

// fin: reduce dp/cp partials -> diag2[c][i], dinv2[c][i]
__global__ void fin_kernel(const float* __restrict__ dp, const float* __restrict__ cp,
                           float* __restrict__ diag2, float* __restrict__ dinv2)
{
  const int idx = blockIdx.x * 256 + threadIdx.x;  // [0, 4096)
  const int c = idx >> 11, i = idx & 2047;
  float ds = 0.f, cs = 0.f;
  for (int b = 0; b < 128; ++b) {
    ds += dp[(size_t)(c * 128 + b) * N2 + i];
    cs += cp[(size_t)(c * 128 + b) * N2 + i];
  }
  const float deg = cs - ds + 1.0f;   // add=True: diag set to 1 contributes +1
  diag2[idx] = ds;
  dinv2[idx] = (deg == 0.f) ? 0.f : 1.f / (deg + 1e-8f);
}

// ---------------------------------------------------------------------------
// T-partials via MFMA: Tp[split][c][i][k] partial of sum_j a1t[i][j]*Yt[c][k][j]
// over j in split's 256-range. M=2048(i), N=64(k), K=2048(j), K-split 8.
// ---------------------------------------------------------------------------
__global__ __launch_bounds__(256) void tgemm_kernel(
    const u16* __restrict__ a1t, const u16* __restrict__ Yt, float* __restrict__ Tp)
{
  const int c = blockIdx.z, split = blockIdx.y;
  const int m0 = blockIdx.x * 128;
  const u16* Ac = a1t + (size_t)c * NN;
  const u16* Bc = Yt + (size_t)c * (64 * (size_t)N2);
  const int t = threadIdx.x, w = t >> 6, lane = t & 63;
  const int quad = lane >> 4, r = lane & 15;
  __shared__ u16 As[128 * 64];
  __shared__ u16 Bs[64 * 64];

  v4f zero4 = { 0.f, 0.f, 0.f, 0.f };
  v4f acc[2][4];
  #pragma unroll
  for (int i = 0; i < 2; ++i)
    #pragma unroll
    for (int j = 0; j < 4; ++j) acc[i][j] = zero4;

  const int srow = lane >> 3;
  const int sgran = (lane & 7) ^ srow;

  for (int kk = 0; kk < 4; ++kk) {
    const int kt = split * 256 + kk * 64;
    __syncthreads();
    #pragma unroll
    for (int i = 0; i < 4; ++i) {
      const int chunk = i * 4 + w;
      const u16* ga = Ac + (size_t)(m0 + chunk * 8 + srow) * N2 + kt + sgran * 8;
      __builtin_amdgcn_global_load_lds((guint*)ga, (luint*)(As + chunk * 512), 16, 0, 0);
    }
    #pragma unroll
    for (int i = 0; i < 2; ++i) {
      const int chunk = i * 4 + w;
      const u16* gb = Bc + (size_t)(chunk * 8 + srow) * N2 + kt + sgran * 8;
      __builtin_amdgcn_global_load_lds((guint*)gb, (luint*)(Bs + chunk * 512), 16, 0, 0);
    }
    __syncthreads();
    #pragma unroll
    for (int ks = 0; ks < 2; ++ks) {
      const int sl = ((ks * 4 + quad) ^ (r & 7)) * 8;
      short8 af[2], bf[4];
      #pragma unroll
      for (int i = 0; i < 2; ++i)
        af[i] = *(const short8*)(As + (w * 32 + i * 16 + r) * 64 + sl);
      #pragma unroll
      for (int j = 0; j < 4; ++j)
        bf[j] = *(const short8*)(Bs + (j * 16 + r) * 64 + sl);
      #pragma unroll
      for (int i = 0; i < 2; ++i)
        #pragma unroll
        for (int j = 0; j < 4; ++j)
          acc[i][j] = __builtin_amdgcn_mfma_f32_16x16x32_bf16(af[i], bf[j], acc[i][j], 0, 0, 0);
    }
  }
  const size_t pbase = (size_t)(split * 2 + c) * 2048;
  #pragma unroll
  for (int i = 0; i < 2; ++i) {
    const int rowg = m0 + w * 32 + i * 16 + quad * 4;
    #pragma unroll
    for (int j = 0; j < 4; ++j) {
      const int colg = j * 16 + r;
      #pragma unroll
      for (int g = 0; g < 4; ++g)
        Tp[(pbase + rowg + g) * 64 + colg] = acc[i][j][g];
    }
  }
}

// out[i][c*64+k] = relu( dinv2 * (T - diag2*xw + xw) ), fp32
__global__ void epilogue_kernel(const float* __restrict__ Tp, const float* __restrict__ diag2,
                                const float* __restrict__ dinv2, const u16* __restrict__ Xwt,
                                float* __restrict__ out)
{
  const int idx = blockIdx.x * 256 + threadIdx.x;
  const int k = idx & 63;
  const int c = (idx >> 6) & 1;
  const int i = idx >> 7;
  float T = 0.f;
  #pragma unroll
  for (int s = 0; s < 8; ++s)
    T += Tp[((size_t)(s * 2 + c) * 2048 + i) * 64 + k];
  const float hd = diag2[c * N2 + i];
  const float dv = dinv2[c * N2 + i];
  const float xw = b2f(Xwt[(size_t)k * N2 + i]);
  float v = dv * (T - hd * xw + xw);
  v = v > 0.f ? v : 0.f;
  out[(size_t)i * 128 + c * 64 + k] = v;
}

// ---------------------------------------------------------------------------
// Workspace layout (bytes), end 84.49 MB, all reads preceded by writes:
//   abf   @ 0          (16.78 MB bf16)  -- dead after gemm1
//   bbt   @ 16777216   (16.78 MB bf16)  -- dead after gemm1
//   a1t   @ 33554432   (16.78 MB bf16)  -- dead after tgemm
//   a1r   @ 50331648   (16.78 MB bf16)  -- dead after dcol
//   Ht    @ 67108864   (16.78 MB bf16)  -- dead after dcol
//   Xwt   @ 83886080   (256 KB bf16 [64][2048])
//   cspa  @ 84148224   (256 KB)
//   diag1 @ 84410368   (16 KB)
//   ci1   @ 84426752   (16 KB)
//   w2v   @ 84443136   (16 KB)
//   diag2 @ 84459520   (16 KB)
//   dinv2 @ 84475904   (16 KB)          -- end 84492288
//   Zp    @ 0          (8.39 MB fp32 [8][2][64][2048], over abf)
//   dp    @ 16777216   (2 MB fp32 [2][128][2048], over bbt)
//   cp    @ 18874368   (2 MB fp32, over bbt)
//   Yt    @ 20971520   (512 KB bf16 [2][64][2048], over bbt)
//   Tp    @ 50331648   (8.39 MB fp32 [8][2][2048][64], over a1r)
// ---------------------------------------------------------------------------
extern "C" void kernel_launch(void* const* d_in, const int* in_sizes, int n_in,
                              void* d_out, int out_size, void* d_ws, size_t ws_size,
                              hipStream_t stream) {
  const float* A  = (const float*)d_in[0];
  const float* X  = (const float*)d_in[1];
  const float* w1 = (const float*)d_in[2];
  const float* w2 = (const float*)d_in[3];
  const float* w3 = (const float*)d_in[4];
  const float* W  = (const float*)d_in[5];
  float* out = (float*)d_out;
  char* ws = (char*)d_ws;

  u16*   abf   = (u16*)(ws + 0);
  u16*   bbt   = (u16*)(ws + 16777216);
  u16*   a1t   = (u16*)(ws + 33554432);
  u16*   a1r   = (u16*)(ws + 50331648);
  u16*   Ht    = (u16*)(ws + 67108864);
  u16*   Xwt   = (u16*)(ws + 83886080);
  float* cspa  = (float*)(ws + 84148224);
  float* diag1 = (float*)(ws + 84410368);
  float* ci1   = (float*)(ws + 84426752);
  float* w2v   = (float*)(ws + 84443136);
  float* diag2 = (float*)(ws + 84459520);
  float* dinv2 = (float*)(ws + 84475904);
  float* Zp    = (float*)(ws + 0);
  float* dp    = (float*)(ws + 16777216);
  float* cp    = (float*)(ws + 18874368);
  u16*   Yt    = (u16*)(ws + 20971520);
  float* Tp    = (float*)(ws + 50331648);

  conv_kernel<<<dim3(32, 32), 512, 0, stream>>>(A, w1, w2, w3, X, W, abf, bbt, a1t, a1r, Xwt);
  gemm_kernel<true><<<dim3(16, 16, 2), 256, 0, stream>>>(abf, bbt, Ht, cspa, diag1);
  zgemm_kernel<<<dim3(16, 8, 2), 256, 0, stream>>>(Ht, Xwt, Zp, cspa, diag1, ci1, w2v);
  dcol_kernel<<<dim3(128, 2), 256, 0, stream>>>(Ht, a1r, ci1, w2v, dp, cp);
  yfix_kernel<<<1024, 256, 0, stream>>>(Zp, ci1, diag1, Xwt, Yt);
  fin_kernel<<<16, 256, 0, stream>>>(dp, cp, diag2, dinv2);
  tgemm_kernel<<<dim3(16, 8, 2), 256, 0, stream>>>(a1t, Yt, Tp);
  epilogue_kernel<<<1024, 256, 0, stream>>>(Tp, diag2, dinv2, Xwt, out);
}